// Round 1
// baseline (205.852 us; speedup 1.0000x reference)
//
#include <hip/hip_runtime.h>
#include <stdint.h>

typedef __bf16 bf16x8 __attribute__((ext_vector_type(8)));
typedef float f32x4 __attribute__((ext_vector_type(4)));
typedef unsigned short u16x8 __attribute__((ext_vector_type(8)));

__device__ __forceinline__ unsigned short f2bf(float f) {
  uint32_t u = __builtin_bit_cast(uint32_t, f);
  u += 0x7FFFu + ((u >> 16) & 1u);   // RNE
  return (unsigned short)(u >> 16);
}
__device__ __forceinline__ float bf2f(unsigned short h) {
  uint32_t u = ((uint32_t)h) << 16;
  return __builtin_bit_cast(float, u);
}

__device__ __forceinline__ void gload_lds16(const void* g, void* l) {
  __builtin_amdgcn_global_load_lds(
      (const __attribute__((address_space(1))) uint32_t*)g,
      (__attribute__((address_space(3))) uint32_t*)l,
      16, 0, 0);
}

// ---------------- convert kernels ----------------

__global__ __launch_bounds__(256) void k_cvt_x(const float* __restrict__ x,
                                               unsigned short* __restrict__ xb, int n4) {
  int stride = gridDim.x * blockDim.x;
  for (int i = blockIdx.x * blockDim.x + threadIdx.x; i < n4; i += stride) {
    float4 v = reinterpret_cast<const float4*>(x)[i];
    ushort4 o;
    o.x = f2bf(v.x); o.y = f2bf(v.y); o.z = f2bf(v.z); o.w = f2bf(v.w);
    reinterpret_cast<ushort4*>(xb)[i] = o;
  }
}

// w: [K][N] f32  ->  wt: [N][K] bf16  (transpose + convert)
__global__ __launch_bounds__(256) void k_cvt_wT(const float* __restrict__ w,
                                                unsigned short* __restrict__ wt, int K, int N) {
  int total = K * N;
  int stride = gridDim.x * blockDim.x;
  for (int i = blockIdx.x * blockDim.x + threadIdx.x; i < total; i += stride) {
    int n = i / K;
    int k = i - n * K;
    wt[i] = f2bf(w[(size_t)k * N + n]);
  }
}

// ---------------- GEMM: C[M,N] = A[M,512] * Bt[N,512]^T ----------------
// 128x128 tile, BK=64, 4 waves (2x2 of 64x64), mfma 16x16x32 bf16.
// LDS tiles stored row-major [128][64] bf16 with 16B-chunk XOR swizzle
// (slot ^= row&7) applied on BOTH the global source address (stage) and the
// ds_read address, LDS dest linear (global_load_lds constraint).
// EPI==0: qkv epilogue -> scatter bf16 q(scaled+bias_rw)/k/v to [B,H,2048,64]
// EPI==1: out epilogue -> f32 C + bias
template <int EPI>
__global__ __launch_bounds__(256) void k_gemm(
    const unsigned short* __restrict__ A,
    const unsigned short* __restrict__ Bt,
    const float* __restrict__ bias,
    const float* __restrict__ brw,
    unsigned short* __restrict__ oq,
    unsigned short* __restrict__ okk,
    unsigned short* __restrict__ ov,
    float* __restrict__ of,
    int Ntiles) {
  __shared__ __align__(128) char lds[32768];
  char* As = lds;
  char* Bs = lds + 16384;

  int bid = blockIdx.x;
  int bm = bid / Ntiles;
  int bn = bid - bm * Ntiles;
  int row0 = bm << 7;
  int col0 = bn << 7;
  int t = threadIdx.x;
  int lane = t & 63;
  int wr = ((t >> 7) & 1) << 6;  // wave row offset
  int wc = ((t >> 6) & 1) << 6;  // wave col offset

  const unsigned short* Ab = A + (size_t)row0 * 512;
  const unsigned short* Bb = Bt + (size_t)col0 * 512;

  f32x4 zero = {0.f, 0.f, 0.f, 0.f};
  f32x4 acc[4][4];
#pragma unroll
  for (int i = 0; i < 4; ++i)
#pragma unroll
    for (int j = 0; j < 4; ++j) acc[i][j] = zero;

  int lr = lane & 15;  // row/col within 16x16 fragment
  int lk = lane >> 4;  // k-group 0..3

#pragma unroll 1
  for (int kt = 0; kt < 8; ++kt) {
    int k0 = kt << 6;
#pragma unroll
    for (int i = 0; i < 4; ++i) {
      int o = (i << 8) + t;  // 16B chunk index 0..1023
      int row = o >> 3;
      int slot = o & 7;
      int gk = k0 + ((slot ^ (row & 7)) << 3);
      gload_lds16(Ab + (size_t)row * 512 + gk, As + (o << 4));
      gload_lds16(Bb + (size_t)row * 512 + gk, Bs + (o << 4));
    }
    __syncthreads();
#pragma unroll
    for (int ks = 0; ks < 2; ++ks) {
      bf16x8 af[4], bfr[4];
      int c = (ks << 2) + lk;
#pragma unroll
      for (int mf = 0; mf < 4; ++mf) {
        int r = wr + (mf << 4) + lr;
        af[mf] = *reinterpret_cast<const bf16x8*>(As + (r << 7) + ((c ^ (r & 7)) << 4));
      }
#pragma unroll
      for (int nf = 0; nf < 4; ++nf) {
        int r = wc + (nf << 4) + lr;
        bfr[nf] = *reinterpret_cast<const bf16x8*>(Bs + (r << 7) + ((c ^ (r & 7)) << 4));
      }
#pragma unroll
      for (int mf = 0; mf < 4; ++mf)
#pragma unroll
        for (int nf = 0; nf < 4; ++nf)
          acc[mf][nf] = __builtin_amdgcn_mfma_f32_16x16x32_bf16(af[mf], bfr[nf], acc[mf][nf], 0, 0, 0);
    }
    __syncthreads();
  }

  if (EPI == 0) {
#pragma unroll
    for (int nf = 0; nf < 4; ++nf) {
      int gc = col0 + wc + (nf << 4) + lr;
      int part = gc >> 9;          // 0=q 1=k 2=v (uniform per block)
      int within = gc & 511;
      int h = within >> 6;
      int e = within & 63;
      float bv = bias[gc];
      float rb = (part == 0) ? brw[within] : 0.f;
      unsigned short* dst = (part == 0) ? oq : (part == 1) ? okk : ov;
#pragma unroll
      for (int mf = 0; mf < 4; ++mf) {
#pragma unroll
        for (int j = 0; j < 4; ++j) {
          int gr = row0 + wr + (mf << 4) + (lane >> 4) * 4 + j;
          int b = gr >> 11;
          int l = gr & 2047;
          float v = acc[mf][nf][j] + bv;
          if (part == 0) v = v * 0.125f + rb;  // hd^-0.5 scale then +bias_rw
          dst[(((size_t)(b * 8 + h) * 2048 + l) << 6) + e] = f2bf(v);
        }
      }
    }
  } else {
#pragma unroll
    for (int mf = 0; mf < 4; ++mf) {
#pragma unroll
      for (int j = 0; j < 4; ++j) {
        int gr = row0 + wr + (mf << 4) + (lane >> 4) * 4 + j;
#pragma unroll
        for (int nf = 0; nf < 4; ++nf) {
          int gc = col0 + wc + (nf << 4) + lr;
          of[(size_t)gr * 512 + gc] = acc[mf][nf][j] + bias[gc];
        }
      }
    }
  }
}

// ---------------- banded attention ----------------
// q/k/v: [B*H][2048][64] bf16.  z: [32768][512] bf16 (col = h*64+e).
// Block: one (b,h) x 64 queries; thread = (query, 16-dim group); 4 lanes/query.
__global__ __launch_bounds__(256) void k_attn(
    const unsigned short* __restrict__ qb,
    const unsigned short* __restrict__ kb,
    const unsigned short* __restrict__ vb,
    unsigned short* __restrict__ zb) {
  int t = threadIdx.x;
  int blk = blockIdx.x;
  int bh = blk >> 5;
  int l0 = (blk & 31) << 6;
  int q = l0 + (t >> 2);
  int dg = t & 3;
  size_t slab = (size_t)bh << 17;  // *2048*64

  const unsigned short* qp = qb + slab + ((size_t)q << 6) + (dg << 4);
  float qv[16];
  {
    u16x8 a = *reinterpret_cast<const u16x8*>(qp);
    u16x8 b = *reinterpret_cast<const u16x8*>(qp + 8);
#pragma unroll
    for (int i = 0; i < 8; ++i) { qv[i] = bf2f(a[i]); qv[8 + i] = bf2f(b[i]); }
  }

  float s[21];
#pragma unroll
  for (int o = 0; o < 21; ++o) {
    int p = q + o - 10;
    int pc = p < 0 ? 0 : (p > 2047 ? 2047 : p);  // clamp for safe load
    const unsigned short* kp = kb + slab + ((size_t)pc << 6) + (dg << 4);
    u16x8 ka = *reinterpret_cast<const u16x8*>(kp);
    u16x8 kb2 = *reinterpret_cast<const u16x8*>(kp + 8);
    float acc = 0.f;
#pragma unroll
    for (int i = 0; i < 8; ++i) acc += qv[i] * bf2f(ka[i]);
#pragma unroll
    for (int i = 0; i < 8; ++i) acc += qv[8 + i] * bf2f(kb2[i]);
    acc += __shfl_xor(acc, 1);
    acc += __shfl_xor(acc, 2);
    s[o] = (p == pc) ? acc : -1e30f;  // mask invalid positions
  }

  float m = -1e30f;
#pragma unroll
  for (int o = 0; o < 21; ++o) m = fmaxf(m, s[o]);
  float sum = 0.f;
#pragma unroll
  for (int o = 0; o < 21; ++o) { s[o] = __expf(s[o] - m); sum += s[o]; }
  float inv = 1.f / sum;

  float z[16];
#pragma unroll
  for (int i = 0; i < 16; ++i) z[i] = 0.f;
#pragma unroll
  for (int o = 0; o < 21; ++o) {
    int p = q + o - 10;
    int pc = p < 0 ? 0 : (p > 2047 ? 2047 : p);
    const unsigned short* vp = vb + slab + ((size_t)pc << 6) + (dg << 4);
    u16x8 va = *reinterpret_cast<const u16x8*>(vp);
    u16x8 vb2 = *reinterpret_cast<const u16x8*>(vp + 8);
    float a = s[o];
#pragma unroll
    for (int i = 0; i < 8; ++i) { z[i] += a * bf2f(va[i]); z[8 + i] += a * bf2f(vb2[i]); }
  }

  int b = bh >> 3, h = bh & 7;
  unsigned short* zp = zb + ((size_t)(b * 2048 + q) << 9) + (h << 6) + (dg << 4);
  u16x8 o0, o1;
#pragma unroll
  for (int i = 0; i < 8; ++i) { o0[i] = f2bf(z[i] * inv); o1[i] = f2bf(z[8 + i] * inv); }
  *reinterpret_cast<u16x8*>(zp) = o0;
  *reinterpret_cast<u16x8*>(zp + 8) = o1;
}

// ---------------- launch ----------------

extern "C" void kernel_launch(void* const* d_in, const int* in_sizes, int n_in,
                              void* d_out, int out_size, void* d_ws, size_t ws_size,
                              hipStream_t stream) {
  (void)in_sizes; (void)n_in; (void)out_size; (void)ws_size;
  const float* x    = (const float*)d_in[0];
  const float* Wqkv = (const float*)d_in[1];
  const float* bqkv = (const float*)d_in[2];
  const float* brw  = (const float*)d_in[3];
  const float* Wout = (const float*)d_in[4];
  const float* bout = (const float*)d_in[5];
  float* out = (float*)d_out;

  // workspace layout (bytes):
  // [0, 32M)      x_bf [32768][512] bf16   — reused as z after GEMM1
  // [32M, +1.5M)  WqkvT [1536][512] bf16
  // [33.5M,+0.5M) WoutT [512][512] bf16
  // [34M+1M, +32M each) q_s, k, v  [16*8][2048][64] bf16
  char* ws = (char*)d_ws;
  unsigned short* xb  = (unsigned short*)(ws);
  unsigned short* wqT = (unsigned short*)(ws + 33554432);
  unsigned short* woT = (unsigned short*)(ws + 35127296);
  unsigned short* qs  = (unsigned short*)(ws + 35651584);
  unsigned short* kbf = (unsigned short*)(ws + 69206016);
  unsigned short* vbf = (unsigned short*)(ws + 102760448);
  unsigned short* zb  = xb;  // safe reuse: x_bf only needed by GEMM1

  k_cvt_x<<<2048, 256, 0, stream>>>(x, xb, 16777216 / 4);
  k_cvt_wT<<<768, 256, 0, stream>>>(Wqkv, wqT, 512, 1536);
  k_cvt_wT<<<256, 256, 0, stream>>>(Wout, woT, 512, 512);
  k_gemm<0><<<3072, 256, 0, stream>>>(xb, wqT, bqkv, brw, qs, kbf, vbf, nullptr, 12);
  k_attn<<<4096, 256, 0, stream>>>(qs, kbf, vbf, zb);
  k_gemm<1><<<1024, 256, 0, stream>>>(zb, woT, bout, nullptr, nullptr, nullptr, nullptr, out, 4);
}

// Round 2
// 194.100 us; speedup vs baseline: 1.0605x; 1.0605x over previous
//
#include <hip/hip_runtime.h>
#include <stdint.h>

typedef __bf16 bf16x8 __attribute__((ext_vector_type(8)));
typedef float f32x4 __attribute__((ext_vector_type(4)));
typedef unsigned short u16x8 __attribute__((ext_vector_type(8)));

__device__ __forceinline__ unsigned short f2bf(float f) {
  uint32_t u = __builtin_bit_cast(uint32_t, f);
  u += 0x7FFFu + ((u >> 16) & 1u);   // RNE
  return (unsigned short)(u >> 16);
}
__device__ __forceinline__ float bf2f(unsigned short h) {
  uint32_t u = ((uint32_t)h) << 16;
  return __builtin_bit_cast(float, u);
}

__device__ __forceinline__ void gload_lds16(const void* g, void* l) {
  __builtin_amdgcn_global_load_lds(
      (const __attribute__((address_space(1))) uint32_t*)g,
      (__attribute__((address_space(3))) uint32_t*)l,
      16, 0, 0);
}

// ---------------- convert kernels ----------------

__global__ __launch_bounds__(256) void k_cvt_x(const float* __restrict__ x,
                                               unsigned short* __restrict__ xb, int n4) {
  int stride = gridDim.x * blockDim.x;
  for (int i = blockIdx.x * blockDim.x + threadIdx.x; i < n4; i += stride) {
    float4 v = reinterpret_cast<const float4*>(x)[i];
    ushort4 o;
    o.x = f2bf(v.x); o.y = f2bf(v.y); o.z = f2bf(v.z); o.w = f2bf(v.w);
    reinterpret_cast<ushort4*>(xb)[i] = o;
  }
}

// w: [K][N] f32  ->  wt: [N][K] bf16  (transpose + convert)
__global__ __launch_bounds__(256) void k_cvt_wT(const float* __restrict__ w,
                                                unsigned short* __restrict__ wt, int K, int N) {
  int total = K * N;
  int stride = gridDim.x * blockDim.x;
  for (int i = blockIdx.x * blockDim.x + threadIdx.x; i < total; i += stride) {
    int n = i / K;
    int k = i - n * K;
    wt[i] = f2bf(w[(size_t)k * N + n]);
  }
}

// ---------------- GEMM: C[M,N] = A[M,512] * Bt[N,512]^T ----------------
// 128x128 tile, BK=64, 4 waves (2x2 of 64x64), mfma 16x16x32 bf16.
// Double-buffered LDS (T3-minimum 2-phase): issue next tile's
// global_load_lds BEFORE computing current tile; one __syncthreads()
// per iteration (its implicit vmcnt(0)+lgkmcnt(0) is the drain).
// 16B-chunk XOR swizzle (slot ^= row&7) on BOTH global source and ds_read
// address, LDS dest linear (global_load_lds constraint, rule #21).
// XCD-aware block swizzle (grid % 8 == 0 for both GEMMs).
// EPI==0: qkv epilogue -> scatter bf16 q(scaled+bias_rw)/k/v to [B,H,2048,64]
// EPI==1: out epilogue -> f32 C + bias
template <int EPI>
__global__ __launch_bounds__(256) void k_gemm(
    const unsigned short* __restrict__ A,
    const unsigned short* __restrict__ Bt,
    const float* __restrict__ bias,
    const float* __restrict__ brw,
    unsigned short* __restrict__ oq,
    unsigned short* __restrict__ okk,
    unsigned short* __restrict__ ov,
    float* __restrict__ of,
    int Ntiles) {
  __shared__ __align__(128) char lds[65536];

  // XCD swizzle: consecutive logical bids (sharing an A row-tile) land on
  // the same XCD's L2. gridDim.x % 8 == 0 guaranteed by launch.
  int cpx = gridDim.x >> 3;
  int bid = (blockIdx.x & 7) * cpx + (blockIdx.x >> 3);
  int bm = bid / Ntiles;
  int bn = bid - bm * Ntiles;
  int row0 = bm << 7;
  int col0 = bn << 7;
  int t = threadIdx.x;
  int lane = t & 63;
  int wr = ((t >> 7) & 1) << 6;  // wave row offset
  int wc = ((t >> 6) & 1) << 6;  // wave col offset

  const unsigned short* Ab = A + (size_t)row0 * 512;
  const unsigned short* Bb = Bt + (size_t)col0 * 512;

  f32x4 zero = {0.f, 0.f, 0.f, 0.f};
  f32x4 acc[4][4];
#pragma unroll
  for (int i = 0; i < 4; ++i)
#pragma unroll
    for (int j = 0; j < 4; ++j) acc[i][j] = zero;

  int lr = lane & 15;  // row/col within 16x16 fragment
  int lk = lane >> 4;  // k-group 0..3

  auto stage = [&](int kt, char* Ad, char* Bd) {
    int k0 = kt << 6;
#pragma unroll
    for (int i = 0; i < 4; ++i) {
      int o = (i << 8) + t;  // 16B chunk index 0..1023
      int row = o >> 3;
      int slot = o & 7;
      int gk = k0 + ((slot ^ (row & 7)) << 3);
      gload_lds16(Ab + (size_t)row * 512 + gk, Ad + (o << 4));
      gload_lds16(Bb + (size_t)row * 512 + gk, Bd + (o << 4));
    }
  };

  auto compute = [&](const char* Ac, const char* Bc) {
#pragma unroll
    for (int ks = 0; ks < 2; ++ks) {
      bf16x8 af[4], bfr[4];
      int c = (ks << 2) + lk;
#pragma unroll
      for (int mf = 0; mf < 4; ++mf) {
        int r = wr + (mf << 4) + lr;
        af[mf] = *reinterpret_cast<const bf16x8*>(Ac + (r << 7) + ((c ^ (r & 7)) << 4));
      }
#pragma unroll
      for (int nf = 0; nf < 4; ++nf) {
        int r = wc + (nf << 4) + lr;
        bfr[nf] = *reinterpret_cast<const bf16x8*>(Bc + (r << 7) + ((c ^ (r & 7)) << 4));
      }
#pragma unroll
      for (int mf = 0; mf < 4; ++mf)
#pragma unroll
        for (int nf = 0; nf < 4; ++nf)
          acc[mf][nf] = __builtin_amdgcn_mfma_f32_16x16x32_bf16(af[mf], bfr[nf], acc[mf][nf], 0, 0, 0);
    }
  };

  char* Ac = lds;
  char* Bc = lds + 16384;
  char* An = lds + 32768;
  char* Bn = lds + 49152;

  stage(0, Ac, Bc);
  __syncthreads();  // implicit vmcnt(0): tile 0 ready

#pragma unroll 1
  for (int kt = 0; kt < 7; ++kt) {
    stage(kt + 1, An, Bn);   // prefetch next tile (latency hides under compute)
    compute(Ac, Bc);
    __syncthreads();         // drains prefetch (vmcnt(0)) + all waves done reading
    char* tp = Ac; Ac = An; An = tp;
    tp = Bc; Bc = Bn; Bn = tp;
  }
  compute(Ac, Bc);

  if (EPI == 0) {
#pragma unroll
    for (int nf = 0; nf < 4; ++nf) {
      int gc = col0 + wc + (nf << 4) + lr;
      int part = gc >> 9;          // 0=q 1=k 2=v (uniform per block)
      int within = gc & 511;
      int h = within >> 6;
      int e = within & 63;
      float bv = bias[gc];
      float rb = (part == 0) ? brw[within] : 0.f;
      unsigned short* dst = (part == 0) ? oq : (part == 1) ? okk : ov;
#pragma unroll
      for (int mf = 0; mf < 4; ++mf) {
#pragma unroll
        for (int j = 0; j < 4; ++j) {
          int gr = row0 + wr + (mf << 4) + (lane >> 4) * 4 + j;
          int b = gr >> 11;
          int l = gr & 2047;
          float v = acc[mf][nf][j] + bv;
          if (part == 0) v = v * 0.125f + rb;  // hd^-0.5 scale then +bias_rw
          dst[(((size_t)(b * 8 + h) * 2048 + l) << 6) + e] = f2bf(v);
        }
      }
    }
  } else {
#pragma unroll
    for (int mf = 0; mf < 4; ++mf) {
#pragma unroll
      for (int j = 0; j < 4; ++j) {
        int gr = row0 + wr + (mf << 4) + (lane >> 4) * 4 + j;
#pragma unroll
        for (int nf = 0; nf < 4; ++nf) {
          int gc = col0 + wc + (nf << 4) + lr;
          of[(size_t)gr * 512 + gc] = acc[mf][nf][j] + bias[gc];
        }
      }
    }
  }
}

// ---------------- banded attention ----------------
// q/k/v: [B*H][2048][64] bf16.  z: [32768][512] bf16 (col = h*64+e).
// Block: one (b,h) x 64 queries; thread = (query, 16-dim group); 4 lanes/query.
__global__ __launch_bounds__(256) void k_attn(
    const unsigned short* __restrict__ qb,
    const unsigned short* __restrict__ kb,
    const unsigned short* __restrict__ vb,
    unsigned short* __restrict__ zb) {
  int t = threadIdx.x;
  int blk = blockIdx.x;
  int bh = blk >> 5;
  int l0 = (blk & 31) << 6;
  int q = l0 + (t >> 2);
  int dg = t & 3;
  size_t slab = (size_t)bh << 17;  // *2048*64

  const unsigned short* qp = qb + slab + ((size_t)q << 6) + (dg << 4);
  float qv[16];
  {
    u16x8 a = *reinterpret_cast<const u16x8*>(qp);
    u16x8 b = *reinterpret_cast<const u16x8*>(qp + 8);
#pragma unroll
    for (int i = 0; i < 8; ++i) { qv[i] = bf2f(a[i]); qv[8 + i] = bf2f(b[i]); }
  }

  float s[21];
#pragma unroll
  for (int o = 0; o < 21; ++o) {
    int p = q + o - 10;
    int pc = p < 0 ? 0 : (p > 2047 ? 2047 : p);  // clamp for safe load
    const unsigned short* kp = kb + slab + ((size_t)pc << 6) + (dg << 4);
    u16x8 ka = *reinterpret_cast<const u16x8*>(kp);
    u16x8 kb2 = *reinterpret_cast<const u16x8*>(kp + 8);
    float acc = 0.f;
#pragma unroll
    for (int i = 0; i < 8; ++i) acc += qv[i] * bf2f(ka[i]);
#pragma unroll
    for (int i = 0; i < 8; ++i) acc += qv[8 + i] * bf2f(kb2[i]);
    acc += __shfl_xor(acc, 1);
    acc += __shfl_xor(acc, 2);
    s[o] = (p == pc) ? acc : -1e30f;  // mask invalid positions
  }

  float m = -1e30f;
#pragma unroll
  for (int o = 0; o < 21; ++o) m = fmaxf(m, s[o]);
  float sum = 0.f;
#pragma unroll
  for (int o = 0; o < 21; ++o) { s[o] = __expf(s[o] - m); sum += s[o]; }
  float inv = 1.f / sum;

  float z[16];
#pragma unroll
  for (int i = 0; i < 16; ++i) z[i] = 0.f;
#pragma unroll
  for (int o = 0; o < 21; ++o) {
    int p = q + o - 10;
    int pc = p < 0 ? 0 : (p > 2047 ? 2047 : p);
    const unsigned short* vp = vb + slab + ((size_t)pc << 6) + (dg << 4);
    u16x8 va = *reinterpret_cast<const u16x8*>(vp);
    u16x8 vb2 = *reinterpret_cast<const u16x8*>(vp + 8);
    float a = s[o];
#pragma unroll
    for (int i = 0; i < 8; ++i) { z[i] += a * bf2f(va[i]); z[8 + i] += a * bf2f(vb2[i]); }
  }

  int b = bh >> 3, h = bh & 7;
  unsigned short* zp = zb + ((size_t)(b * 2048 + q) << 9) + (h << 6) + (dg << 4);
  u16x8 o0, o1;
#pragma unroll
  for (int i = 0; i < 8; ++i) { o0[i] = f2bf(z[i] * inv); o1[i] = f2bf(z[8 + i] * inv); }
  *reinterpret_cast<u16x8*>(zp) = o0;
  *reinterpret_cast<u16x8*>(zp + 8) = o1;
}

// ---------------- launch ----------------

extern "C" void kernel_launch(void* const* d_in, const int* in_sizes, int n_in,
                              void* d_out, int out_size, void* d_ws, size_t ws_size,
                              hipStream_t stream) {
  (void)in_sizes; (void)n_in; (void)out_size; (void)ws_size;
  const float* x    = (const float*)d_in[0];
  const float* Wqkv = (const float*)d_in[1];
  const float* bqkv = (const float*)d_in[2];
  const float* brw  = (const float*)d_in[3];
  const float* Wout = (const float*)d_in[4];
  const float* bout = (const float*)d_in[5];
  float* out = (float*)d_out;

  // workspace layout (bytes):
  // [0, 32M)      x_bf [32768][512] bf16   — reused as z after GEMM1
  // [32M, +1.5M)  WqkvT [1536][512] bf16
  // [33.5M,+0.5M) WoutT [512][512] bf16
  // [34M, +32M each) q_s, k, v  [16*8][2048][64] bf16
  char* ws = (char*)d_ws;
  unsigned short* xb  = (unsigned short*)(ws);
  unsigned short* wqT = (unsigned short*)(ws + 33554432);
  unsigned short* woT = (unsigned short*)(ws + 35127296);
  unsigned short* qs  = (unsigned short*)(ws + 35651584);
  unsigned short* kbf = (unsigned short*)(ws + 69206016);
  unsigned short* vbf = (unsigned short*)(ws + 102760448);
  unsigned short* zb  = xb;  // safe reuse: x_bf only needed by GEMM1

  k_cvt_x<<<2048, 256, 0, stream>>>(x, xb, 16777216 / 4);
  k_cvt_wT<<<768, 256, 0, stream>>>(Wqkv, wqT, 512, 1536);
  k_cvt_wT<<<256, 256, 0, stream>>>(Wout, woT, 512, 512);
  k_gemm<0><<<3072, 256, 0, stream>>>(xb, wqT, bqkv, brw, qs, kbf, vbf, nullptr, 12);
  k_attn<<<4096, 256, 0, stream>>>(qs, kbf, vbf, zb);
  k_gemm<1><<<1024, 256, 0, stream>>>(zb, woT, bout, nullptr, nullptr, nullptr, nullptr, out, 4);
}

// Round 3
// 189.245 us; speedup vs baseline: 1.0878x; 1.0257x over previous
//
#include <hip/hip_runtime.h>
#include <stdint.h>

typedef __bf16 bf16x8 __attribute__((ext_vector_type(8)));
typedef float f32x4 __attribute__((ext_vector_type(4)));
typedef unsigned short u16x8 __attribute__((ext_vector_type(8)));

__device__ __forceinline__ unsigned short f2bf(float f) {
  uint32_t u = __builtin_bit_cast(uint32_t, f);
  u += 0x7FFFu + ((u >> 16) & 1u);   // RNE
  return (unsigned short)(u >> 16);
}
__device__ __forceinline__ float bf2f(unsigned short h) {
  uint32_t u = ((uint32_t)h) << 16;
  return __builtin_bit_cast(float, u);
}

__device__ __forceinline__ void gload_lds16(const void* g, void* l) {
  __builtin_amdgcn_global_load_lds(
      (const __attribute__((address_space(1))) uint32_t*)g,
      (__attribute__((address_space(3))) uint32_t*)l,
      16, 0, 0);
}

// ---------------- convert kernels ----------------

__global__ __launch_bounds__(256) void k_cvt_x(const float* __restrict__ x,
                                               unsigned short* __restrict__ xb, int n4) {
  int stride = gridDim.x * blockDim.x;
  for (int i = blockIdx.x * blockDim.x + threadIdx.x; i < n4; i += stride) {
    float4 v = reinterpret_cast<const float4*>(x)[i];
    ushort4 o;
    o.x = f2bf(v.x); o.y = f2bf(v.y); o.z = f2bf(v.z); o.w = f2bf(v.w);
    reinterpret_cast<ushort4*>(xb)[i] = o;
  }
}

// w: [K][N] f32  ->  wt: [N][K] bf16  (transpose + convert)
__global__ __launch_bounds__(256) void k_cvt_wT(const float* __restrict__ w,
                                                unsigned short* __restrict__ wt, int K, int N) {
  int total = K * N;
  int stride = gridDim.x * blockDim.x;
  for (int i = blockIdx.x * blockDim.x + threadIdx.x; i < total; i += stride) {
    int n = i / K;
    int k = i - n * K;
    wt[i] = f2bf(w[(size_t)k * N + n]);
  }
}

// ---------------- GEMM1: 256x256 tile, 4-phase/K-tile, qkv epilogue -------
// C[M,1536] = A[M,512] * Bt[1536,512]^T.  BM=BN=256, BK=64, 8 waves (2Mx4N),
// wave-tile 128x64. LDS: dbuf A(2x32K) + B(2x32K) = 128KB.
// Per K-tile: 4 phases (mh = p&1, ks = p>>1):
//   { ds_read A-quad (4xb128) [+ B 4xb128 when mh==0] ; stage {3,3,2,0} of
//     next K-tile ; s_barrier ; setprio(1) 16xMFMA setprio(0) ;
//     [p==3: vmcnt(0)] ; s_barrier }
// Raw barriers keep prefetch in flight across phases (T3/T4); one counted
// drain per K-tile. 16B-chunk XOR swizzle (slot ^= row&7) on global source
// + ds_read addr, LDS dest linear (rule #21). XCD-aware bid swizzle.
// Epilogue: LDS-bounce per-wave 16KB region -> coalesced 16B stores.
__global__ __launch_bounds__(512, 2) void k_gemm256_qkv(
    const unsigned short* __restrict__ A,
    const unsigned short* __restrict__ Bt,
    const float* __restrict__ bias,
    const float* __restrict__ brw,
    unsigned short* __restrict__ oq,
    unsigned short* __restrict__ okk,
    unsigned short* __restrict__ ov,
    int Ntiles) {
  __shared__ __align__(128) char lds[131072];

  int cpx = gridDim.x >> 3;
  int bid = (blockIdx.x & 7) * cpx + (blockIdx.x >> 3);
  int bm = bid / Ntiles;
  int bn = bid - bm * Ntiles;
  int row0 = bm << 8;
  int col0 = bn << 8;
  int t = threadIdx.x;
  int lane = t & 63;
  int w = t >> 6;        // wave 0..7
  int wm = w >> 2;       // 0..1
  int wn = w & 3;        // 0..3
  int lr = lane & 15;
  int lk = lane >> 4;

  const unsigned short* Ab = A + (size_t)row0 * 512;
  const unsigned short* Bb = Bt + (size_t)col0 * 512;

  f32x4 zero = {0.f, 0.f, 0.f, 0.f};
  f32x4 acc[8][4];
#pragma unroll
  for (int i = 0; i < 8; ++i)
#pragma unroll
    for (int j = 0; j < 4; ++j) acc[i][j] = zero;

  // stage instruction s (0..7) of K-tile kt into dbuf nd.
  // s 0..3 = A chunks, s 4..7 = B chunks; each stages 512 threads x 16B = 8KB.
  auto stage2 = [&](int s, int nd, int kt) {
    int matrix = s >> 2;
    int o = ((s & 3) << 9) + t;       // 16B-chunk index 0..2047
    int row = o >> 3;                 // 0..255
    int slot = o & 7;
    int gk = (kt << 6) + ((slot ^ (row & 7)) << 3);
    const unsigned short* src = (matrix ? Bb : Ab) + (size_t)row * 512 + gk;
    char* dstl = lds + (matrix ? 65536 : 0) + (nd << 15) + (o << 4);
    gload_lds16(src, dstl);
  };

  // prologue: stage K-tile 0 into buffer 0
#pragma unroll
  for (int s = 0; s < 8; ++s) stage2(s, 0, 0);
  asm volatile("s_waitcnt vmcnt(0)" ::: "memory");
  __builtin_amdgcn_s_barrier();

#pragma unroll 1
  for (int kt = 0; kt < 8; ++kt) {
    const char* Abuf = lds + ((kt & 1) << 15);
    const char* Bbuf = lds + 65536 + ((kt & 1) << 15);
    int nd = (kt & 1) ^ 1;
    bf16x8 bfs[4];
#pragma unroll
    for (int p = 0; p < 4; ++p) {
      int ks = p >> 1;
      int mh = p & 1;
      int c = (ks << 2) + lk;
      if (mh == 0) {
#pragma unroll
        for (int nf = 0; nf < 4; ++nf) {
          int rB = (wn << 6) + (nf << 4) + lr;
          bfs[nf] = *reinterpret_cast<const bf16x8*>(Bbuf + (rB << 7) + ((c ^ (rB & 7)) << 4));
        }
      }
      bf16x8 af[4];
#pragma unroll
      for (int mf2 = 0; mf2 < 4; ++mf2) {
        int rA = (wm << 7) + (mh << 6) + (mf2 << 4) + lr;
        af[mf2] = *reinterpret_cast<const bf16x8*>(Abuf + (rA << 7) + ((c ^ (rA & 7)) << 4));
      }
      if (kt < 7) {
        // stage counts per phase {3,3,2,0}: all 8 issued >=1 phase before drain
        if (p == 0) { stage2(0, nd, kt + 1); stage2(1, nd, kt + 1); stage2(2, nd, kt + 1); }
        if (p == 1) { stage2(3, nd, kt + 1); stage2(4, nd, kt + 1); stage2(5, nd, kt + 1); }
        if (p == 2) { stage2(6, nd, kt + 1); stage2(7, nd, kt + 1); }
      }
      __builtin_amdgcn_s_barrier();
      __builtin_amdgcn_s_setprio(1);
#pragma unroll
      for (int mf2 = 0; mf2 < 4; ++mf2)
#pragma unroll
        for (int nf = 0; nf < 4; ++nf)
          acc[(mh << 2) + mf2][nf] =
              __builtin_amdgcn_mfma_f32_16x16x32_bf16(af[mf2], bfs[nf], acc[(mh << 2) + mf2][nf], 0, 0, 0);
      __builtin_amdgcn_s_setprio(0);
      if (p == 3) asm volatile("s_waitcnt vmcnt(0)" ::: "memory");
      __builtin_amdgcn_s_barrier();
    }
  }

  // ---- epilogue: LDS-bounce then coalesced stores ----
  // final phase-3 barrier ordered all reads before the region overwrite.
  char* ep = lds + (w << 14);  // 16KB per wave: [128 rows][64 cols] bf16, chunk-XOR swizzled
  int gc0 = col0 + (wn << 6);
  int part = gc0 >> 9;              // 0=q 1=k 2=v (uniform per wave)
  int hh = (gc0 & 511) >> 6;
  unsigned short* dst = (part == 0) ? oq : (part == 1) ? okk : ov;
  float bvv[4], rbv[4];
#pragma unroll
  for (int nf = 0; nf < 4; ++nf) {
    int cc = (nf << 4) + lr;
    bvv[nf] = bias[gc0 + cc];
    rbv[nf] = (part == 0) ? brw[(gc0 & 511) + cc] : 0.f;
  }
#pragma unroll
  for (int mf = 0; mf < 8; ++mf) {
#pragma unroll
    for (int nf = 0; nf < 4; ++nf) {
      int cc = (nf << 4) + lr;
#pragma unroll
      for (int j = 0; j < 4; ++j) {
        int r = (mf << 4) + ((lane >> 4) << 2) + j;
        float v = acc[mf][nf][j] + bvv[nf];
        if (part == 0) v = v * 0.125f + rbv[nf];
        int byte = (r << 7) + ((((cc >> 3) ^ (r & 7))) << 4) + ((cc & 7) << 1);
        *reinterpret_cast<unsigned short*>(ep + byte) = f2bf(v);
      }
    }
  }
  asm volatile("s_waitcnt lgkmcnt(0)" ::: "memory");
  __builtin_amdgcn_sched_barrier(0);
  int b0 = row0 >> 11;
  size_t base = (size_t)(b0 * 8 + hh) * 2048;
#pragma unroll
  for (int i = 0; i < 16; ++i) {
    int rr = (i << 3) + (lane >> 3);
    int ch = lane & 7;
    int byte = (rr << 7) + ((ch ^ (rr & 7)) << 4);
    u16x8 val = *reinterpret_cast<const u16x8*>(ep + byte);
    int gl = (row0 + (wm << 7) + rr) & 2047;
    *reinterpret_cast<u16x8*>(dst + ((base + gl) << 6) + (ch << 3)) = val;
  }
}

// ---------------- GEMM (128x128, old structure) — used for GEMM2 ----------
template <int EPI>
__global__ __launch_bounds__(256) void k_gemm(
    const unsigned short* __restrict__ A,
    const unsigned short* __restrict__ Bt,
    const float* __restrict__ bias,
    const float* __restrict__ brw,
    unsigned short* __restrict__ oq,
    unsigned short* __restrict__ okk,
    unsigned short* __restrict__ ov,
    float* __restrict__ of,
    int Ntiles) {
  __shared__ __align__(128) char lds[65536];

  int cpx = gridDim.x >> 3;
  int bid = (blockIdx.x & 7) * cpx + (blockIdx.x >> 3);
  int bm = bid / Ntiles;
  int bn = bid - bm * Ntiles;
  int row0 = bm << 7;
  int col0 = bn << 7;
  int t = threadIdx.x;
  int lane = t & 63;
  int wr = ((t >> 7) & 1) << 6;
  int wc = ((t >> 6) & 1) << 6;

  const unsigned short* Ab = A + (size_t)row0 * 512;
  const unsigned short* Bb = Bt + (size_t)col0 * 512;

  f32x4 zero = {0.f, 0.f, 0.f, 0.f};
  f32x4 acc[4][4];
#pragma unroll
  for (int i = 0; i < 4; ++i)
#pragma unroll
    for (int j = 0; j < 4; ++j) acc[i][j] = zero;

  int lr = lane & 15;
  int lk = lane >> 4;

  auto stage = [&](int kt, char* Ad, char* Bd) {
    int k0 = kt << 6;
#pragma unroll
    for (int i = 0; i < 4; ++i) {
      int o = (i << 8) + t;
      int row = o >> 3;
      int slot = o & 7;
      int gk = k0 + ((slot ^ (row & 7)) << 3);
      gload_lds16(Ab + (size_t)row * 512 + gk, Ad + (o << 4));
      gload_lds16(Bb + (size_t)row * 512 + gk, Bd + (o << 4));
    }
  };

  auto compute = [&](const char* Ac, const char* Bc) {
#pragma unroll
    for (int ks = 0; ks < 2; ++ks) {
      bf16x8 af[4], bfr[4];
      int c = (ks << 2) + lk;
#pragma unroll
      for (int mf = 0; mf < 4; ++mf) {
        int r = wr + (mf << 4) + lr;
        af[mf] = *reinterpret_cast<const bf16x8*>(Ac + (r << 7) + ((c ^ (r & 7)) << 4));
      }
#pragma unroll
      for (int nf = 0; nf < 4; ++nf) {
        int r = wc + (nf << 4) + lr;
        bfr[nf] = *reinterpret_cast<const bf16x8*>(Bc + (r << 7) + ((c ^ (r & 7)) << 4));
      }
#pragma unroll
      for (int mf = 0; mf < 4; ++mf)
#pragma unroll
        for (int nf = 0; nf < 4; ++nf)
          acc[mf][nf] = __builtin_amdgcn_mfma_f32_16x16x32_bf16(af[mf], bfr[nf], acc[mf][nf], 0, 0, 0);
    }
  };

  char* Ac = lds;
  char* Bc = lds + 16384;
  char* An = lds + 32768;
  char* Bn = lds + 49152;

  stage(0, Ac, Bc);
  __syncthreads();

#pragma unroll 1
  for (int kt = 0; kt < 7; ++kt) {
    stage(kt + 1, An, Bn);
    compute(Ac, Bc);
    __syncthreads();
    char* tp = Ac; Ac = An; An = tp;
    tp = Bc; Bc = Bn; Bn = tp;
  }
  compute(Ac, Bc);

  if (EPI == 0) {
#pragma unroll
    for (int nf = 0; nf < 4; ++nf) {
      int gc = col0 + wc + (nf << 4) + lr;
      int part = gc >> 9;
      int within = gc & 511;
      int h = within >> 6;
      int e = within & 63;
      float bv = bias[gc];
      float rb = (part == 0) ? brw[within] : 0.f;
      unsigned short* dst = (part == 0) ? oq : (part == 1) ? okk : ov;
#pragma unroll
      for (int mf = 0; mf < 4; ++mf) {
#pragma unroll
        for (int j = 0; j < 4; ++j) {
          int gr = row0 + wr + (mf << 4) + (lane >> 4) * 4 + j;
          int b = gr >> 11;
          int l = gr & 2047;
          float v = acc[mf][nf][j] + bv;
          if (part == 0) v = v * 0.125f + rb;
          dst[(((size_t)(b * 8 + h) * 2048 + l) << 6) + e] = f2bf(v);
        }
      }
    }
  } else {
#pragma unroll
    for (int mf = 0; mf < 4; ++mf) {
#pragma unroll
      for (int j = 0; j < 4; ++j) {
        int gr = row0 + wr + (mf << 4) + (lane >> 4) * 4 + j;
#pragma unroll
        for (int nf = 0; nf < 4; ++nf) {
          int gc = col0 + wc + (nf << 4) + lr;
          of[(size_t)gr * 512 + gc] = acc[mf][nf][j] + bias[gc];
        }
      }
    }
  }
}

// ---------------- banded attention ----------------
__global__ __launch_bounds__(256) void k_attn(
    const unsigned short* __restrict__ qb,
    const unsigned short* __restrict__ kb,
    const unsigned short* __restrict__ vb,
    unsigned short* __restrict__ zb) {
  int t = threadIdx.x;
  int blk = blockIdx.x;
  int bh = blk >> 5;
  int l0 = (blk & 31) << 6;
  int q = l0 + (t >> 2);
  int dg = t & 3;
  size_t slab = (size_t)bh << 17;

  const unsigned short* qp = qb + slab + ((size_t)q << 6) + (dg << 4);
  float qv[16];
  {
    u16x8 a = *reinterpret_cast<const u16x8*>(qp);
    u16x8 b = *reinterpret_cast<const u16x8*>(qp + 8);
#pragma unroll
    for (int i = 0; i < 8; ++i) { qv[i] = bf2f(a[i]); qv[8 + i] = bf2f(b[i]); }
  }

  float s[21];
#pragma unroll
  for (int o = 0; o < 21; ++o) {
    int p = q + o - 10;
    int pc = p < 0 ? 0 : (p > 2047 ? 2047 : p);
    const unsigned short* kp = kb + slab + ((size_t)pc << 6) + (dg << 4);
    u16x8 ka = *reinterpret_cast<const u16x8*>(kp);
    u16x8 kb2 = *reinterpret_cast<const u16x8*>(kp + 8);
    float acc = 0.f;
#pragma unroll
    for (int i = 0; i < 8; ++i) acc += qv[i] * bf2f(ka[i]);
#pragma unroll
    for (int i = 0; i < 8; ++i) acc += qv[8 + i] * bf2f(kb2[i]);
    acc += __shfl_xor(acc, 1);
    acc += __shfl_xor(acc, 2);
    s[o] = (p == pc) ? acc : -1e30f;
  }

  float m = -1e30f;
#pragma unroll
  for (int o = 0; o < 21; ++o) m = fmaxf(m, s[o]);
  float sum = 0.f;
#pragma unroll
  for (int o = 0; o < 21; ++o) { s[o] = __expf(s[o] - m); sum += s[o]; }
  float inv = 1.f / sum;

  float z[16];
#pragma unroll
  for (int i = 0; i < 16; ++i) z[i] = 0.f;
#pragma unroll
  for (int o = 0; o < 21; ++o) {
    int p = q + o - 10;
    int pc = p < 0 ? 0 : (p > 2047 ? 2047 : p);
    const unsigned short* vp = vb + slab + ((size_t)pc << 6) + (dg << 4);
    u16x8 va = *reinterpret_cast<const u16x8*>(vp);
    u16x8 vb2 = *reinterpret_cast<const u16x8*>(vp + 8);
    float a = s[o];
#pragma unroll
    for (int i = 0; i < 8; ++i) { z[i] += a * bf2f(va[i]); z[8 + i] += a * bf2f(vb2[i]); }
  }

  int b = bh >> 3, h = bh & 7;
  unsigned short* zp = zb + ((size_t)(b * 2048 + q) << 9) + (h << 6) + (dg << 4);
  u16x8 o0, o1;
#pragma unroll
  for (int i = 0; i < 8; ++i) { o0[i] = f2bf(z[i] * inv); o1[i] = f2bf(z[8 + i] * inv); }
  *reinterpret_cast<u16x8*>(zp) = o0;
  *reinterpret_cast<u16x8*>(zp + 8) = o1;
}

// ---------------- launch ----------------

extern "C" void kernel_launch(void* const* d_in, const int* in_sizes, int n_in,
                              void* d_out, int out_size, void* d_ws, size_t ws_size,
                              hipStream_t stream) {
  (void)in_sizes; (void)n_in; (void)out_size; (void)ws_size;
  const float* x    = (const float*)d_in[0];
  const float* Wqkv = (const float*)d_in[1];
  const float* bqkv = (const float*)d_in[2];
  const float* brw  = (const float*)d_in[3];
  const float* Wout = (const float*)d_in[4];
  const float* bout = (const float*)d_in[5];
  float* out = (float*)d_out;

  char* ws = (char*)d_ws;
  unsigned short* xb  = (unsigned short*)(ws);
  unsigned short* wqT = (unsigned short*)(ws + 33554432);
  unsigned short* woT = (unsigned short*)(ws + 35127296);
  unsigned short* qs  = (unsigned short*)(ws + 35651584);
  unsigned short* kbf = (unsigned short*)(ws + 69206016);
  unsigned short* vbf = (unsigned short*)(ws + 102760448);
  unsigned short* zb  = xb;  // safe reuse: x_bf only needed by GEMM1

  k_cvt_x<<<2048, 256, 0, stream>>>(x, xb, 16777216 / 4);
  k_cvt_wT<<<768, 256, 0, stream>>>(Wqkv, wqT, 512, 1536);
  k_cvt_wT<<<256, 256, 0, stream>>>(Wout, woT, 512, 512);
  k_gemm256_qkv<<<768, 512, 0, stream>>>(xb, wqT, bqkv, brw, qs, kbf, vbf, 6);
  k_attn<<<4096, 256, 0, stream>>>(qs, kbf, vbf, zb);
  k_gemm<1><<<1024, 256, 0, stream>>>(zb, woT, bout, nullptr, nullptr, nullptr, nullptr, out, 4);
}